// Round 6
// baseline (1248.485 us; speedup 1.0000x reference)
//
#include <hip/hip_runtime.h>
#include <hip/hip_bf16.h>
#include <stdint.h>

// Problem constants: [T,B,D]=[4096,4,1024], H=4096. f32 inputs, f32 outputs.
// Outputs: soft [B,T] f32 at out[0..16384), hard [B,T] f32 at out[16384..32768).
#define T_STEPS 4096
#define BATCH   4
#define D_IN    1024
#define H_DIM   4096
#define M_ROWS  (T_STEPS * BATCH)

typedef __attribute__((ext_vector_type(8))) short bf16x8;
typedef __attribute__((ext_vector_type(4))) float f32x4;

__device__ __forceinline__ float b2f(unsigned short u) {
    union { unsigned int i; float f; } x; x.i = ((unsigned int)u) << 16; return x.f;
}
__device__ __forceinline__ unsigned short f2bf_rne(float f) {
    union { float f; unsigned int u; } v; v.f = f;
    return (unsigned short)((v.u + 0x7FFFu + ((v.u >> 16) & 1u)) >> 16);
}

__device__ __forceinline__ void load_lds16(const unsigned short* g, unsigned short* l) {
    __builtin_amdgcn_global_load_lds(
        (const __attribute__((address_space(1))) void*)g,
        (__attribute__((address_space(3))) void*)l, 16, 0, 0);
}

// ---------------- prep: split X (fat blocks) + split/transpose W + zero logits ----------------
// blocks [0,4096): split_x (4 float4/thread) | [4096,6144): split_w | [6144,6176): zero logits
__global__ void __launch_bounds__(256)
prep(const float* __restrict__ hidden,
     const float* __restrict__ Wb1, const float* __restrict__ Wr1,
     unsigned short* __restrict__ Xhi, unsigned short* __restrict__ Xlo,
     unsigned short* __restrict__ WThi, unsigned short* __restrict__ WTlo,
     float* __restrict__ logits)
{
    __shared__ float tile[64][65];
    const int bid = blockIdx.x;
    const int t = threadIdx.x;

    if (bid < 4096) {
        // split hidden f32 -> (hi, lo) bf16, same layout; 4 coalesced float4 per thread
#pragma unroll
        for (int j = 0; j < 4; ++j) {
            int i = bid * 1024 + j * 256 + t;
            float4 x = ((const float4*)hidden)[i];
            ushort4 h, l;
            h.x = f2bf_rne(x.x); l.x = f2bf_rne(x.x - b2f(h.x));
            h.y = f2bf_rne(x.y); l.y = f2bf_rne(x.y - b2f(h.y));
            h.z = f2bf_rne(x.z); l.z = f2bf_rne(x.z - b2f(h.z));
            h.w = f2bf_rne(x.w); l.w = f2bf_rne(x.w - b2f(h.w));
            ((ushort4*)Xhi)[i] = h;
            ((ushort4*)Xlo)[i] = l;
        }
    } else if (bid < 6144) {
        // transpose+split W [D][H] -> WT [H][D] for both matrices
        int wb  = bid - 4096;
        int z   = wb >> 10;                   // 0=boundary, 1=reset
        int rem = wb & 1023;
        int bx  = (rem & 63) * 64;            // H direction
        int by  = (rem >> 6) * 64;            // D direction
        const float* src = z ? Wr1 : Wb1;
        const size_t moff = (size_t)z * H_DIM * D_IN;
        const int c4 = (t & 15) * 4;
        const int r0 = (t >> 4) * 4;
#pragma unroll
        for (int rr = 0; rr < 4; ++rr) {
            int r = r0 + rr;
            float4 v = *(const float4*)(src + (size_t)(by + r) * H_DIM + bx + c4);
            tile[r][c4 + 0] = v.x; tile[r][c4 + 1] = v.y;
            tile[r][c4 + 2] = v.z; tile[r][c4 + 3] = v.w;
        }
        __syncthreads();
#pragma unroll
        for (int rr = 0; rr < 4; ++rr) {
            int c = r0 + rr;
            ushort4 h, l;
            float f0 = tile[c4 + 0][c], f1 = tile[c4 + 1][c];
            float f2 = tile[c4 + 2][c], f3 = tile[c4 + 3][c];
            h.x = f2bf_rne(f0); l.x = f2bf_rne(f0 - b2f(h.x));
            h.y = f2bf_rne(f1); l.y = f2bf_rne(f1 - b2f(h.y));
            h.z = f2bf_rne(f2); l.z = f2bf_rne(f2 - b2f(h.z));
            h.w = f2bf_rne(f3); l.w = f2bf_rne(f3 - b2f(h.w));
            size_t o = moff + (size_t)(bx + c) * D_IN + by + c4;
            *(ushort4*)(WThi + o) = h;
            *(ushort4*)(WTlo + o) = l;
        }
    } else {
#pragma unroll
        for (int j = 0; j < 4; ++j)
            logits[(bid - 6144) * 1024 + j * 256 + t] = 0.f;   // 32 blocks x 1024 = 32768
    }
}

// ------------- fused split-f32 GEMM + relu + (.)@W2 reduction -------------
// Evidence from rounds 0/1/5: MFMA busy is pinned at the ~397us pipe floor in every
// variant; stall tracks MFMA-work-per-barrier-phase (96/phase -> 622us, 48/phase ->
// 795-830us), not dbuf or blocks/CU. This round combines 96 MFMA/phase AND dbuf:
//   BM=BN=256, BK=32, 512 thr / 8 waves, wave tile 128m x 64n (8x4 frags x 3 = 96).
//   Per-buffer LDS = (256+256)*32*4B = 64 KB; dbuf 128 KB -> 1 block/CU, 8 waves/CU
//   (same TLP as round 0's 2x4). Staging/output traffic per elem drops 1.5 -> 1.0 B.
// All proven micro-geometry kept verbatim: 64B rows, 0-conflict XOR swizzle
// (phys 16B chunk = logical ^ ((row>>1)&3)), staging dest = t*16B (wave-uniform +
// lane*16), 16x16x32 MFMA, same product order -> bit-identical per-output FP chains.
__global__ void __launch_bounds__(512, 2)
gemm_fused3(const unsigned short* __restrict__ Xhi, const unsigned short* __restrict__ Xlo,
            const unsigned short* __restrict__ WThi, const unsigned short* __restrict__ WTlo,
            const float* __restrict__ b1b, const float* __restrict__ b1r,
            const float* __restrict__ w2b, const float* __restrict__ w2r,
            float* __restrict__ logits)              // [2][B][T] f32, atomically accumulated
{
    // per-buffer layout (ushort offsets): Ahi [0,8192) | Alo [8192,16384) |
    // Bhi [16384,24576) | Blo [24576,32768). 64 KB per buffer, 128 KB total.
    __shared__ __align__(16) unsigned short S0[32768];
    __shared__ __align__(16) unsigned short S1[32768];

    const int t    = threadIdx.x;
    const int wave = t >> 6;
    const int lane = t & 63;
    const int quad = lane >> 4;
    const int lr   = lane & 15;
    const int wm   = (wave & 1) * 128;       // wave tile 128m x 64n
    const int wn   = (wave >> 1) * 64;

    const int mat = blockIdx.z;
    const int n0  = blockIdx.x * 256;
    const int m0  = blockIdx.y * 256;

    const size_t aoff = (size_t)m0 * D_IN;
    const size_t boff = (size_t)mat * H_DIM * D_IN + (size_t)n0 * D_IN;
    const unsigned short* Ah = Xhi + aoff;
    const unsigned short* Al = Xlo + aoff;
    const unsigned short* Bh = WThi + boff;
    const unsigned short* Bl = WTlo + boff;
    const float* b1 = mat ? b1r : b1b;
    const float* w2 = mat ? w2r : w2b;
    float* out = logits + mat * M_ROWS;

    // staging (BK=32, 512 threads): thread t fills phys chunk (t&3) of row (t>>2)+i*128.
    // Source global chunk = (t&3) ^ ((row>>1)&3) = (t&3) ^ ((t>>3)&3)   [proven formula].
    // LDS dest = t*16B within each 8KB half-subarray: wave-uniform base + lane*16. ✓
    const int srow = t >> 2;                              // 0..127
    const int scol = (((t & 3) ^ ((t >> 3) & 3)) * 8);
    const int tt8  = t * 8;                               // dest ushort offset

#define STAGE(S, kt_)                                                           \
    do {                                                                        \
        const int k0_ = (kt_) * 32;                                             \
        _Pragma("unroll") for (int i = 0; i < 2; ++i)                           \
            load_lds16(Ah + (size_t)(i * 128 + srow) * D_IN + k0_ + scol,       \
                       (S) + i * 4096 + tt8);                                   \
        _Pragma("unroll") for (int i = 0; i < 2; ++i)                           \
            load_lds16(Al + (size_t)(i * 128 + srow) * D_IN + k0_ + scol,       \
                       (S) + 8192 + i * 4096 + tt8);                            \
        _Pragma("unroll") for (int i = 0; i < 2; ++i)                           \
            load_lds16(Bh + (size_t)(i * 128 + srow) * D_IN + k0_ + scol,       \
                       (S) + 16384 + i * 4096 + tt8);                           \
        _Pragma("unroll") for (int i = 0; i < 2; ++i)                           \
            load_lds16(Bl + (size_t)(i * 128 + srow) * D_IN + k0_ + scol,       \
                       (S) + 24576 + i * 4096 + tt8);                           \
    } while (0)

    // fragment read offsets (loop-invariant); proven conflict-free swizzle, rows < 256
    int afo[8], bfo[4];
#pragma unroll
    for (int i = 0; i < 8; ++i) {
        int ra = wm + i * 16 + lr;
        afo[i] = ra * 32 + ((quad ^ ((ra >> 1) & 3)) * 8);
    }
#pragma unroll
    for (int j = 0; j < 4; ++j) {
        int rb = wn + j * 16 + lr;
        bfo[j] = rb * 32 + ((quad ^ ((rb >> 1) & 3)) * 8);
    }

    f32x4 acc[8][4] = {};

#define COMPUTE(S)                                                              \
    do {                                                                        \
        bf16x8 afh[8], afl[8], bfh[4], bfl[4];                                  \
        _Pragma("unroll") for (int j = 0; j < 4; ++j) {                         \
            bfh[j] = *(const bf16x8*)((S) + 16384 + bfo[j]);                    \
            bfl[j] = *(const bf16x8*)((S) + 24576 + bfo[j]);                    \
        }                                                                       \
        _Pragma("unroll") for (int i = 0; i < 8; ++i) {                         \
            afh[i] = *(const bf16x8*)((S) + afo[i]);                            \
            afl[i] = *(const bf16x8*)((S) + 8192 + afo[i]);                     \
        }                                                                       \
        _Pragma("unroll") for (int i = 0; i < 8; ++i)                           \
        _Pragma("unroll") for (int j = 0; j < 4; ++j)                           \
            acc[i][j] = __builtin_amdgcn_mfma_f32_16x16x32_bf16(afh[i], bfh[j], acc[i][j], 0, 0, 0); \
        _Pragma("unroll") for (int i = 0; i < 8; ++i)                           \
        _Pragma("unroll") for (int j = 0; j < 4; ++j)                           \
            acc[i][j] = __builtin_amdgcn_mfma_f32_16x16x32_bf16(afl[i], bfh[j], acc[i][j], 0, 0, 0); \
        _Pragma("unroll") for (int i = 0; i < 8; ++i)                           \
        _Pragma("unroll") for (int j = 0; j < 4; ++j)                           \
            acc[i][j] = __builtin_amdgcn_mfma_f32_16x16x32_bf16(afh[i], bfl[j], acc[i][j], 0, 0, 0); \
    } while (0)

    STAGE(S0, 0);
    __syncthreads();                          // prologue drain (auto vmcnt(0))

#pragma unroll 1
    for (int kt = 0; kt < D_IN / 32; kt += 2) {
        STAGE(S1, kt + 1);                    // prefetch next chunk into other buffer
        COMPUTE(S0);                          // 96 MFMA (~3700 cyc/CU) cover stage latency
        __syncthreads();                      // auto vmcnt(0): S1 ready, S0 reads done
        if (kt + 2 < D_IN / 32) STAGE(S0, kt + 2);
        COMPUTE(S1);
        __syncthreads();
    }

    // epilogue: relu(C + b1)*w2, reduce over this tile's n, accumulate to logits
    float b1v[4], w2v[4];
#pragma unroll
    for (int j = 0; j < 4; ++j) {
        int n = n0 + wn + j * 16 + lr;               // C/D col = lane&15
        b1v[j] = b1[n];
        w2v[j] = w2[n];
    }
#pragma unroll
    for (int i = 0; i < 8; ++i) {
#pragma unroll
        for (int r = 0; r < 4; ++r) {
            float s = 0.f;
#pragma unroll
            for (int j = 0; j < 4; ++j) {
                float h = acc[i][j][r] + b1v[j];
                s += fmaxf(h, 0.f) * w2v[j];
            }
            s += __shfl_xor(s, 1, 64);
            s += __shfl_xor(s, 2, 64);
            s += __shfl_xor(s, 4, 64);
            s += __shfl_xor(s, 8, 64);
            if (lr == 0) {
                int m = m0 + wm + i * 16 + quad * 4 + r;   // C/D row = quad*4 + reg
                atomicAdd(&out[(m & (BATCH - 1)) * T_STEPS + (m >> 2)], s);  // -> [b][t]
            }
        }
    }
#undef STAGE
#undef COMPUTE
}

// ------------- finish: soft output (blocks 0..63) + serial LIF scan (block 64) -------------
// Scan is a 4096-step serial chain; loads are L2-latency-bound if issued in-chain.
// Fix: 16-step register prefetch ring (load chunk c+1 before processing chunk c;
// ~250 cyc of chain work hides the ~200 cyc L2 latency). x+bb2 / rl>0 computed off-chain.
__global__ void __launch_bounds__(256)
finish(const float* __restrict__ logits,
       const float* __restrict__ bb2p, const float* __restrict__ br2p,
       float* __restrict__ out)
{
    if (blockIdx.x < 64) {
        int i = blockIdx.x * 256 + threadIdx.x;
        out[i] = logits[i] + bb2p[0];                // soft = boundary logits [b][t] + bb2
        return;
    }
    int b = threadIdx.x;
    if (b >= BATCH) return;
    const float bb2 = bb2p[0];
    const float br2 = br2p[0];
    const float* xb = logits + b * T_STEPS;          // boundary logits, [b][t]
    const float* xr = logits + M_ROWS + b * T_STEPS; // reset logits
    float* hb = out + M_ROWS + b * T_STEPS;

    float4 cx[4], cr[4], nx[4] = {}, nr[4] = {};
#pragma unroll
    for (int q = 0; q < 4; ++q) {
        cx[q] = *(const float4*)(xb + q * 4);
        cr[q] = *(const float4*)(xr + q * 4);
    }

    float v = 0.f;
    for (int t0 = 0; t0 < T_STEPS; t0 += 16) {
        if (t0 + 16 < T_STEPS) {
#pragma unroll
            for (int q = 0; q < 4; ++q) {
                nx[q] = *(const float4*)(xb + t0 + 16 + q * 4);
                nr[q] = *(const float4*)(xr + t0 + 16 + q * 4);
            }
        }
#pragma unroll
        for (int q = 0; q < 4; ++q) {
            // off-chain precompute (same ops as before, just hoisted)
            float xs[4] = { cx[q].x + bb2, cx[q].y + bb2, cx[q].z + bb2, cx[q].w + bb2 };
            bool  rm[4] = { cr[q].x + br2 > 0.f, cr[q].y + br2 > 0.f,
                            cr[q].z + br2 > 0.f, cr[q].w + br2 > 0.f };
            float4 sv;
#pragma unroll
            for (int u = 0; u < 4; ++u) {
                v = v + (xs[u] - v) * 0.5f;          // bit-identical to reference step
                bool spike = (v >= 1.0f);
                ((float*)&sv)[u] = spike ? 1.0f : 0.0f;
                v = (spike || rm[u]) ? 0.f : v;
            }
            *(float4*)(hb + t0 + q * 4) = sv;
        }
#pragma unroll
        for (int q = 0; q < 4; ++q) { cx[q] = nx[q]; cr[q] = nr[q]; }
    }
}

extern "C" void kernel_launch(void* const* d_in, const int* in_sizes, int n_in,
                              void* d_out, int out_size, void* d_ws, size_t ws_size,
                              hipStream_t stream) {
    // dict order (confirmed): hidden, Wb1, bb1, Wb2, bb2, Wr1, br1, Wr2, br2
    const float* hidden = (const float*)d_in[0];   // [T,B,D] f32
    const float* Wb1    = (const float*)d_in[1];   // [D,H]
    const float* bb1    = (const float*)d_in[2];   // [H]
    const float* Wb2    = (const float*)d_in[3];   // [H,1]
    const float* bb2    = (const float*)d_in[4];   // [1]
    const float* Wr1    = (const float*)d_in[5];
    const float* br1    = (const float*)d_in[6];
    const float* Wr2    = (const float*)d_in[7];
    const float* br2    = (const float*)d_in[8];
    float* out = (float*)d_out;                    // f32: [soft B*T][hard B*T]

    // ws layout (96.13 MB): Xhi 32MB | Xlo 32MB | WThi 16MB | WTlo 16MB | logits 128KB
    unsigned short* Xhi  = (unsigned short*)d_ws;
    unsigned short* Xlo  = Xhi  + (size_t)M_ROWS * D_IN;
    unsigned short* WThi = Xlo  + (size_t)M_ROWS * D_IN;
    unsigned short* WTlo = WThi + (size_t)2 * H_DIM * D_IN;
    float* logits = (float*)(WTlo + (size_t)2 * H_DIM * D_IN);

    prep<<<dim3(6176), 256, 0, stream>>>(hidden, Wb1, Wr1, Xhi, Xlo, WThi, WTlo, logits);
    gemm_fused3<<<dim3(H_DIM / 256, M_ROWS / 256, 2), 512, 0, stream>>>(
        Xhi, Xlo, WThi, WTlo, bb1, br1, Wb2, Wr2, logits);
    finish<<<dim3(65), 256, 0, stream>>>(logits, bb2, br2, out);
}

// Round 8
// 1004.165 us; speedup vs baseline: 1.2433x; 1.2433x over previous
//
#include <hip/hip_runtime.h>
#include <hip/hip_bf16.h>
#include <stdint.h>

// Problem constants: [T,B,D]=[4096,4,1024], H=4096. f32 inputs, f32 outputs.
// Outputs: soft [B,T] f32 at out[0..16384), hard [B,T] f32 at out[16384..32768).
#define T_STEPS 4096
#define BATCH   4
#define D_IN    1024
#define H_DIM   4096
#define M_ROWS  (T_STEPS * BATCH)

typedef __attribute__((ext_vector_type(8))) short bf16x8;
typedef __attribute__((ext_vector_type(4))) float f32x4;

__device__ __forceinline__ float b2f(unsigned short u) {
    union { unsigned int i; float f; } x; x.i = ((unsigned int)u) << 16; return x.f;
}
__device__ __forceinline__ unsigned short f2bf_rne(float f) {
    union { float f; unsigned int u; } v; v.f = f;
    return (unsigned short)((v.u + 0x7FFFu + ((v.u >> 16) & 1u)) >> 16);
}

__device__ __forceinline__ void load_lds16(const unsigned short* g, unsigned short* l) {
    __builtin_amdgcn_global_load_lds(
        (const __attribute__((address_space(1))) void*)g,
        (__attribute__((address_space(3))) void*)l, 16, 0, 0);
}

// ---------------- prep: split X (fat blocks) + split/transpose W + zero logits ----------------
// blocks [0,4096): split_x (4 float4/thread) | [4096,6144): split_w | [6144,6176): zero logits
__global__ void __launch_bounds__(256)
prep(const float* __restrict__ hidden,
     const float* __restrict__ Wb1, const float* __restrict__ Wr1,
     unsigned short* __restrict__ Xhi, unsigned short* __restrict__ Xlo,
     unsigned short* __restrict__ WThi, unsigned short* __restrict__ WTlo,
     float* __restrict__ logits)
{
    __shared__ float tile[64][65];
    const int bid = blockIdx.x;
    const int t = threadIdx.x;

    if (bid < 4096) {
        // split hidden f32 -> (hi, lo) bf16, same layout; 4 coalesced float4 per thread
#pragma unroll
        for (int j = 0; j < 4; ++j) {
            int i = bid * 1024 + j * 256 + t;
            float4 x = ((const float4*)hidden)[i];
            ushort4 h, l;
            h.x = f2bf_rne(x.x); l.x = f2bf_rne(x.x - b2f(h.x));
            h.y = f2bf_rne(x.y); l.y = f2bf_rne(x.y - b2f(h.y));
            h.z = f2bf_rne(x.z); l.z = f2bf_rne(x.z - b2f(h.z));
            h.w = f2bf_rne(x.w); l.w = f2bf_rne(x.w - b2f(h.w));
            ((ushort4*)Xhi)[i] = h;
            ((ushort4*)Xlo)[i] = l;
        }
    } else if (bid < 6144) {
        // transpose+split W [D][H] -> WT [H][D] for both matrices
        int wb  = bid - 4096;
        int z   = wb >> 10;                   // 0=boundary, 1=reset
        int rem = wb & 1023;
        int bx  = (rem & 63) * 64;            // H direction
        int by  = (rem >> 6) * 64;            // D direction
        const float* src = z ? Wr1 : Wb1;
        const size_t moff = (size_t)z * H_DIM * D_IN;
        const int c4 = (t & 15) * 4;
        const int r0 = (t >> 4) * 4;
#pragma unroll
        for (int rr = 0; rr < 4; ++rr) {
            int r = r0 + rr;
            float4 v = *(const float4*)(src + (size_t)(by + r) * H_DIM + bx + c4);
            tile[r][c4 + 0] = v.x; tile[r][c4 + 1] = v.y;
            tile[r][c4 + 2] = v.z; tile[r][c4 + 3] = v.w;
        }
        __syncthreads();
#pragma unroll
        for (int rr = 0; rr < 4; ++rr) {
            int c = r0 + rr;
            ushort4 h, l;
            float f0 = tile[c4 + 0][c], f1 = tile[c4 + 1][c];
            float f2 = tile[c4 + 2][c], f3 = tile[c4 + 3][c];
            h.x = f2bf_rne(f0); l.x = f2bf_rne(f0 - b2f(h.x));
            h.y = f2bf_rne(f1); l.y = f2bf_rne(f1 - b2f(h.y));
            h.z = f2bf_rne(f2); l.z = f2bf_rne(f2 - b2f(h.z));
            h.w = f2bf_rne(f3); l.w = f2bf_rne(f3 - b2f(h.w));
            size_t o = moff + (size_t)(bx + c) * D_IN + by + c4;
            *(ushort4*)(WThi + o) = h;
            *(ushort4*)(WTlo + o) = l;
        }
    } else {
#pragma unroll
        for (int j = 0; j < 4; ++j)
            logits[(bid - 6144) * 1024 + j * 256 + t] = 0.f;   // 32 blocks x 1024 = 32768
    }
}

// ------------- fused split-f32 GEMM + relu + (.)@W2 reduction -------------
// Round 6 retry WITHOUT the register-spill confound (R6: WRITE_SIZE 16->313 MB = scratch).
// Evidence r0/r1/r5: MFMA busy pinned ~380-400us everywhere; stall tracks MFMA/phase
// (96/phase -> 622us, 48/phase -> 795-830us). This kernel: 96 MFMA/phase AND dbuf.
//   BM=BN=256, BK=32, 512 thr / 8 waves; wave tile = R0's 64m x 128n ORIENTATION
//   (wm=(wave&3)*64, wn=(wave>>2)*128) -> frags 4A*2 + 8B*2 = 96 VGPR + 128 acc ~ 240,
//   R0's PROVEN register budget (R6's 128x64 tile needed ~272 -> spilled).
//   Per-buffer LDS = 4 arrays x 256 rows x 64B = 64 KB; dbuf 128 KB -> 1 block/CU,
//   8 waves/CU (same TLP as R0's 2 blocks x 4 waves).
// Micro-geometry verbatim from R0/R6 (both measured 0 conflicts): 64B rows, XOR swizzle
// phys16Bchunk = logical ^ ((row>>1)&3), staging dest = t*16B, 16x16x32 MFMA,
// same product order -> bit-identical per-output FP chains (absmax 0.0039).
__global__ void __launch_bounds__(512, 2)
gemm_fused3(const unsigned short* __restrict__ Xhi, const unsigned short* __restrict__ Xlo,
            const unsigned short* __restrict__ WThi, const unsigned short* __restrict__ WTlo,
            const float* __restrict__ b1b, const float* __restrict__ b1r,
            const float* __restrict__ w2b, const float* __restrict__ w2r,
            float* __restrict__ logits)              // [2][B][T] f32, atomically accumulated
{
    // per-buffer layout (ushort offsets): Ahi [0,8192) | Alo [8192,16384) |
    // Bhi [16384,24576) | Blo [24576,32768). 64 KB per buffer, 128 KB total.
    __shared__ __align__(16) unsigned short S0[32768];
    __shared__ __align__(16) unsigned short S1[32768];

    const int t    = threadIdx.x;
    const int wave = t >> 6;
    const int lane = t & 63;
    const int quad = lane >> 4;
    const int lr   = lane & 15;
    const int wm   = (wave & 3) * 64;        // 4 m-positions: wave tile 64m x 128n
    const int wn   = (wave >> 2) * 128;      // 2 n-positions

    const int mat = blockIdx.z;
    const int n0  = blockIdx.x * 256;
    const int m0  = blockIdx.y * 256;

    const size_t aoff = (size_t)m0 * D_IN;
    const size_t boff = (size_t)mat * H_DIM * D_IN + (size_t)n0 * D_IN;
    const unsigned short* Ah = Xhi + aoff;
    const unsigned short* Al = Xlo + aoff;
    const unsigned short* Bh = WThi + boff;
    const unsigned short* Bl = WTlo + boff;
    const float* b1 = mat ? b1r : b1b;
    const float* w2 = mat ? w2r : w2b;
    float* out = logits + mat * M_ROWS;

    // staging (BK=32, 512 threads): thread t fills phys chunk (t&3) of rows (t>>2)+i*128.
    // Source global chunk = (t&3) ^ ((row>>1)&3) = (t&3) ^ ((t>>3)&3)  [proven formula;
    // row+128 keeps the same XOR since 128>>1 = 64 == 0 mod 4].
    // LDS dest = t*16B within each 8KB half-subarray: wave-uniform base + lane*16. ✓
    const int srow = t >> 2;                              // 0..127
    const int scol = (((t & 3) ^ ((t >> 3) & 3)) * 8);
    const int tt8  = t * 8;                               // dest ushort offset

#define STAGE(S, kt_)                                                           \
    do {                                                                        \
        const int k0_ = (kt_) * 32;                                             \
        _Pragma("unroll") for (int i = 0; i < 2; ++i)                           \
            load_lds16(Ah + (size_t)(i * 128 + srow) * D_IN + k0_ + scol,       \
                       (S) + i * 4096 + tt8);                                   \
        _Pragma("unroll") for (int i = 0; i < 2; ++i)                           \
            load_lds16(Al + (size_t)(i * 128 + srow) * D_IN + k0_ + scol,       \
                       (S) + 8192 + i * 4096 + tt8);                            \
        _Pragma("unroll") for (int i = 0; i < 2; ++i)                           \
            load_lds16(Bh + (size_t)(i * 128 + srow) * D_IN + k0_ + scol,       \
                       (S) + 16384 + i * 4096 + tt8);                           \
        _Pragma("unroll") for (int i = 0; i < 2; ++i)                           \
            load_lds16(Bl + (size_t)(i * 128 + srow) * D_IN + k0_ + scol,       \
                       (S) + 24576 + i * 4096 + tt8);                           \
    } while (0)

    // fragment read offsets (loop-invariant); proven conflict-free swizzle, rows < 256
    int afo[4], bfo[8];
#pragma unroll
    for (int i = 0; i < 4; ++i) {
        int ra = wm + i * 16 + lr;
        afo[i] = ra * 32 + ((quad ^ ((ra >> 1) & 3)) * 8);
    }
#pragma unroll
    for (int j = 0; j < 8; ++j) {
        int rb = wn + j * 16 + lr;
        bfo[j] = rb * 32 + ((quad ^ ((rb >> 1) & 3)) * 8);
    }

    f32x4 acc[4][8] = {};

#define COMPUTE(S)                                                              \
    do {                                                                        \
        bf16x8 afh[4], afl[4], bfh[8], bfl[8];                                  \
        _Pragma("unroll") for (int i = 0; i < 4; ++i) {                         \
            afh[i] = *(const bf16x8*)((S) + afo[i]);                            \
            afl[i] = *(const bf16x8*)((S) + 8192 + afo[i]);                     \
        }                                                                       \
        _Pragma("unroll") for (int j = 0; j < 8; ++j) {                         \
            bfh[j] = *(const bf16x8*)((S) + 16384 + bfo[j]);                    \
            bfl[j] = *(const bf16x8*)((S) + 24576 + bfo[j]);                    \
        }                                                                       \
        _Pragma("unroll") for (int i = 0; i < 4; ++i)                           \
        _Pragma("unroll") for (int j = 0; j < 8; ++j)                           \
            acc[i][j] = __builtin_amdgcn_mfma_f32_16x16x32_bf16(afh[i], bfh[j], acc[i][j], 0, 0, 0); \
        _Pragma("unroll") for (int i = 0; i < 4; ++i)                           \
        _Pragma("unroll") for (int j = 0; j < 8; ++j)                           \
            acc[i][j] = __builtin_amdgcn_mfma_f32_16x16x32_bf16(afl[i], bfh[j], acc[i][j], 0, 0, 0); \
        _Pragma("unroll") for (int i = 0; i < 4; ++i)                           \
        _Pragma("unroll") for (int j = 0; j < 8; ++j)                           \
            acc[i][j] = __builtin_amdgcn_mfma_f32_16x16x32_bf16(afh[i], bfl[j], acc[i][j], 0, 0, 0); \
    } while (0)

    STAGE(S0, 0);
    __syncthreads();                          // prologue drain (auto vmcnt(0))

#pragma unroll 1
    for (int kt = 0; kt < D_IN / 32; kt += 2) {
        STAGE(S1, kt + 1);                    // prefetch next chunk into other buffer
        COMPUTE(S0);                          // 96 MFMA (~3700 cyc/CU) cover stage latency
        __syncthreads();                      // auto vmcnt(0): S1 ready, S0 reads done
        if (kt + 2 < D_IN / 32) STAGE(S0, kt + 2);
        COMPUTE(S1);
        __syncthreads();
    }

    // epilogue: relu(C + b1)*w2, reduce over this tile's n, accumulate to logits
    float b1v[8], w2v[8];
#pragma unroll
    for (int j = 0; j < 8; ++j) {
        int n = n0 + wn + j * 16 + lr;               // C/D col = lane&15
        b1v[j] = b1[n];
        w2v[j] = w2[n];
    }
#pragma unroll
    for (int i = 0; i < 4; ++i) {
#pragma unroll
        for (int r = 0; r < 4; ++r) {
            float s = 0.f;
#pragma unroll
            for (int j = 0; j < 8; ++j) {
                float h = acc[i][j][r] + b1v[j];
                s += fmaxf(h, 0.f) * w2v[j];
            }
            s += __shfl_xor(s, 1, 64);
            s += __shfl_xor(s, 2, 64);
            s += __shfl_xor(s, 4, 64);
            s += __shfl_xor(s, 8, 64);
            if (lr == 0) {
                int m = m0 + wm + i * 16 + quad * 4 + r;   // C/D row = quad*4 + reg
                atomicAdd(&out[(m & (BATCH - 1)) * T_STEPS + (m >> 2)], s);  // -> [b][t]
            }
        }
    }
#undef STAGE
#undef COMPUTE
}

// ------------- finish: soft output (blocks 0..63) + serial LIF scan (block 64) -------------
// Scan is a 4096-step serial chain; loads are L2-latency-bound if issued in-chain.
// Fix: 16-step register prefetch ring (load chunk c+1 before processing chunk c;
// ~250 cyc of chain work hides the ~200 cyc L2 latency). x+bb2 / rl>0 computed off-chain.
__global__ void __launch_bounds__(256)
finish(const float* __restrict__ logits,
       const float* __restrict__ bb2p, const float* __restrict__ br2p,
       float* __restrict__ out)
{
    if (blockIdx.x < 64) {
        int i = blockIdx.x * 256 + threadIdx.x;
        out[i] = logits[i] + bb2p[0];                // soft = boundary logits [b][t] + bb2
        return;
    }
    int b = threadIdx.x;
    if (b >= BATCH) return;
    const float bb2 = bb2p[0];
    const float br2 = br2p[0];
    const float* xb = logits + b * T_STEPS;          // boundary logits, [b][t]
    const float* xr = logits + M_ROWS + b * T_STEPS; // reset logits
    float* hb = out + M_ROWS + b * T_STEPS;

    float4 cx[4], cr[4], nx[4] = {}, nr[4] = {};
#pragma unroll
    for (int q = 0; q < 4; ++q) {
        cx[q] = *(const float4*)(xb + q * 4);
        cr[q] = *(const float4*)(xr + q * 4);
    }

    float v = 0.f;
    for (int t0 = 0; t0 < T_STEPS; t0 += 16) {
        if (t0 + 16 < T_STEPS) {
#pragma unroll
            for (int q = 0; q < 4; ++q) {
                nx[q] = *(const float4*)(xb + t0 + 16 + q * 4);
                nr[q] = *(const float4*)(xr + t0 + 16 + q * 4);
            }
        }
#pragma unroll
        for (int q = 0; q < 4; ++q) {
            // off-chain precompute (same ops as before, just hoisted)
            float xs[4] = { cx[q].x + bb2, cx[q].y + bb2, cx[q].z + bb2, cx[q].w + bb2 };
            bool  rm[4] = { cr[q].x + br2 > 0.f, cr[q].y + br2 > 0.f,
                            cr[q].z + br2 > 0.f, cr[q].w + br2 > 0.f };
            float4 sv;
#pragma unroll
            for (int u = 0; u < 4; ++u) {
                v = v + (xs[u] - v) * 0.5f;          // bit-identical to reference step
                bool spike = (v >= 1.0f);
                ((float*)&sv)[u] = spike ? 1.0f : 0.0f;
                v = (spike || rm[u]) ? 0.f : v;
            }
            *(float4*)(hb + t0 + q * 4) = sv;
        }
#pragma unroll
        for (int q = 0; q < 4; ++q) { cx[q] = nx[q]; cr[q] = nr[q]; }
    }
}

extern "C" void kernel_launch(void* const* d_in, const int* in_sizes, int n_in,
                              void* d_out, int out_size, void* d_ws, size_t ws_size,
                              hipStream_t stream) {
    // dict order (confirmed): hidden, Wb1, bb1, Wb2, bb2, Wr1, br1, Wr2, br2
    const float* hidden = (const float*)d_in[0];   // [T,B,D] f32
    const float* Wb1    = (const float*)d_in[1];   // [D,H]
    const float* bb1    = (const float*)d_in[2];   // [H]
    const float* Wb2    = (const float*)d_in[3];   // [H,1]
    const float* bb2    = (const float*)d_in[4];   // [1]
    const float* Wr1    = (const float*)d_in[5];
    const float* br1    = (const float*)d_in[6];
    const float* Wr2    = (const float*)d_in[7];
    const float* br2    = (const float*)d_in[8];
    float* out = (float*)d_out;                    // f32: [soft B*T][hard B*T]

    // ws layout (96.13 MB): Xhi 32MB | Xlo 32MB | WThi 16MB | WTlo 16MB | logits 128KB
    unsigned short* Xhi  = (unsigned short*)d_ws;
    unsigned short* Xlo  = Xhi  + (size_t)M_ROWS * D_IN;
    unsigned short* WThi = Xlo  + (size_t)M_ROWS * D_IN;
    unsigned short* WTlo = WThi + (size_t)2 * H_DIM * D_IN;
    float* logits = (float*)(WTlo + (size_t)2 * H_DIM * D_IN);

    prep<<<dim3(6176), 256, 0, stream>>>(hidden, Wb1, Wr1, Xhi, Xlo, WThi, WTlo, logits);
    gemm_fused3<<<dim3(H_DIM / 256, M_ROWS / 256, 2), 512, 0, stream>>>(
        Xhi, Xlo, WThi, WTlo, bb1, br1, Wb2, Wr2, logits);
    finish<<<dim3(65), 256, 0, stream>>>(logits, bb2, br2, out);
}

// Round 9
// 741.503 us; speedup vs baseline: 1.6837x; 1.3542x over previous
//
#include <hip/hip_runtime.h>
#include <hip/hip_bf16.h>
#include <stdint.h>

// Problem constants: [T,B,D]=[4096,4,1024], H=4096. f32 inputs, f32 outputs.
// Outputs: soft [B,T] f32 at out[0..16384), hard [B,T] f32 at out[16384..32768).
#define T_STEPS 4096
#define BATCH   4
#define D_IN    1024
#define H_DIM   4096
#define M_ROWS  (T_STEPS * BATCH)

typedef __attribute__((ext_vector_type(8))) short bf16x8;
typedef __attribute__((ext_vector_type(4))) float f32x4;

__device__ __forceinline__ float b2f(unsigned short u) {
    union { unsigned int i; float f; } x; x.i = ((unsigned int)u) << 16; return x.f;
}
__device__ __forceinline__ unsigned short f2bf_rne(float f) {
    union { float f; unsigned int u; } v; v.f = f;
    return (unsigned short)((v.u + 0x7FFFu + ((v.u >> 16) & 1u)) >> 16);
}

__device__ __forceinline__ void load_lds16(const unsigned short* g, unsigned short* l) {
    __builtin_amdgcn_global_load_lds(
        (const __attribute__((address_space(1))) void*)g,
        (__attribute__((address_space(3))) void*)l, 16, 0, 0);
}

// ---------------- prep: split X (fat blocks) + split/transpose W + zero logits ----------------
// blocks [0,4096): split_x (4 float4/thread) | [4096,6144): split_w (HI ONLY) | [6144,6176): zero
// WTlo removed: the Xhi*Blo product is dropped in the GEMM (see gemm_fused2 comment), so the
// W low-half is never consumed -> skip its compute and 16 MB of writes.
__global__ void __launch_bounds__(256)
prep(const float* __restrict__ hidden,
     const float* __restrict__ Wb1, const float* __restrict__ Wr1,
     unsigned short* __restrict__ Xhi, unsigned short* __restrict__ Xlo,
     unsigned short* __restrict__ WThi,
     float* __restrict__ logits)
{
    __shared__ float tile[64][65];
    const int bid = blockIdx.x;
    const int t = threadIdx.x;

    if (bid < 4096) {
        // split hidden f32 -> (hi, lo) bf16, same layout; 4 coalesced float4 per thread
#pragma unroll
        for (int j = 0; j < 4; ++j) {
            int i = bid * 1024 + j * 256 + t;
            float4 x = ((const float4*)hidden)[i];
            ushort4 h, l;
            h.x = f2bf_rne(x.x); l.x = f2bf_rne(x.x - b2f(h.x));
            h.y = f2bf_rne(x.y); l.y = f2bf_rne(x.y - b2f(h.y));
            h.z = f2bf_rne(x.z); l.z = f2bf_rne(x.z - b2f(h.z));
            h.w = f2bf_rne(x.w); l.w = f2bf_rne(x.w - b2f(h.w));
            ((ushort4*)Xhi)[i] = h;
            ((ushort4*)Xlo)[i] = l;
        }
    } else if (bid < 6144) {
        // transpose W [D][H] -> WT [H][D] for both matrices, bf16 hi only
        int wb  = bid - 4096;
        int z   = wb >> 10;                   // 0=boundary, 1=reset
        int rem = wb & 1023;
        int bx  = (rem & 63) * 64;            // H direction
        int by  = (rem >> 6) * 64;            // D direction
        const float* src = z ? Wr1 : Wb1;
        const size_t moff = (size_t)z * H_DIM * D_IN;
        const int c4 = (t & 15) * 4;
        const int r0 = (t >> 4) * 4;
#pragma unroll
        for (int rr = 0; rr < 4; ++rr) {
            int r = r0 + rr;
            float4 v = *(const float4*)(src + (size_t)(by + r) * H_DIM + bx + c4);
            tile[r][c4 + 0] = v.x; tile[r][c4 + 1] = v.y;
            tile[r][c4 + 2] = v.z; tile[r][c4 + 3] = v.w;
        }
        __syncthreads();
#pragma unroll
        for (int rr = 0; rr < 4; ++rr) {
            int c = r0 + rr;
            ushort4 h;
            h.x = f2bf_rne(tile[c4 + 0][c]);
            h.y = f2bf_rne(tile[c4 + 1][c]);
            h.z = f2bf_rne(tile[c4 + 2][c]);
            h.w = f2bf_rne(tile[c4 + 3][c]);
            size_t o = moff + (size_t)(bx + c) * D_IN + by + c4;
            *(ushort4*)(WThi + o) = h;
        }
    } else {
#pragma unroll
        for (int j = 0; j < 4; ++j)
            logits[(bid - 6144) * 1024 + j * 256 + t] = 0.f;   // 32 blocks x 1024 = 32768
    }
}

// ------------- fused split-f32 GEMM + relu + (.)@W2 reduction, 2 PRODUCTS -------------
// R0 STRUCTURE VERBATIM (proven optimum of the 2-barrier family after 5 failed variants:
// r1/r5 dbuf=795-830, r4 32x32=800, r8 big-tile dbuf=794 vs r0=622; MFMA busy pinned
// 365-400us in all). Change: DROP the Xhi*Blo product set (was LAST in r0's accumulation
// order -> remaining per-output FP chain is a bit-identical PREFIX of r0's).
// Error budget: |Xhi*Blo| term ~1e-3 in h -> ~1e-3 on logits; r3 PASSED at absmax 0.0078,
// current 0.0039 -> predicted ~0.005-0.007. FLOP floor 397 -> 265 us.
// Also removes: Blo staging (12->8 load_lds16/chunk), Blo LDS (48->32 KB), WTlo (prep).
__global__ void __launch_bounds__(256, 2)
gemm_fused2(const unsigned short* __restrict__ Xhi, const unsigned short* __restrict__ Xlo,
            const unsigned short* __restrict__ WThi,
            const float* __restrict__ b1b, const float* __restrict__ b1r,
            const float* __restrict__ w2b, const float* __restrict__ w2r,
            float* __restrict__ logits)              // [2][B][T] f32, atomically accumulated
{
    __shared__ __align__(16) unsigned short Ahi_s[128 * 32];   // 8 KB
    __shared__ __align__(16) unsigned short Alo_s[128 * 32];   // 8 KB
    __shared__ __align__(16) unsigned short Bhi_s[256 * 32];   // 16 KB

    const int t    = threadIdx.x;
    const int wave = t >> 6;
    const int lane = t & 63;
    const int quad = lane >> 4;
    const int lr   = lane & 15;
    const int w_m  = (wave & 1) * 64;
    const int w_n  = (wave >> 1) * 128;

    const int mat = blockIdx.z;
    const int n0  = blockIdx.x * 256;
    const int m0  = blockIdx.y * 128;

    const size_t aoff = (size_t)m0 * D_IN;
    const size_t boff = (size_t)mat * H_DIM * D_IN + (size_t)n0 * D_IN;
    const unsigned short* Ah = Xhi + aoff;
    const unsigned short* Al = Xlo + aoff;
    const unsigned short* Bh = WThi + boff;
    const float* b1 = mat ? b1r : b1b;
    const float* w2 = mat ? w2r : w2b;
    float* out = logits + mat * M_ROWS;

    // staging (BK=32, r0 verbatim): thread t fills phys chunk (t&3) of row (t>>2)+i*64.
    // Source global chunk = (t&3) ^ ((row>>1)&3) = (t&3) ^ ((t>>3)&3).
    const int srow = t >> 2;
    const int scol = (((t & 3) ^ ((t >> 3) & 3)) * 8);

    f32x4 acc[4][8] = {};

#pragma unroll 1
    for (int kt = 0; kt < D_IN / 32; ++kt) {
        const int k0 = kt * 32;
#pragma unroll
        for (int i = 0; i < 2; ++i)
            load_lds16(Ah + (size_t)(i * 64 + srow) * D_IN + k0 + scol, Ahi_s + i * 2048 + wave * 512);
#pragma unroll
        for (int i = 0; i < 2; ++i)
            load_lds16(Al + (size_t)(i * 64 + srow) * D_IN + k0 + scol, Alo_s + i * 2048 + wave * 512);
#pragma unroll
        for (int i = 0; i < 4; ++i)
            load_lds16(Bh + (size_t)(i * 64 + srow) * D_IN + k0 + scol, Bhi_s + i * 2048 + wave * 512);
        __syncthreads();

        // all fragment loads up front; compiler issues fine-grained lgkmcnt per MFMA set
        bf16x8 afh[4], afl[4], bfh[8];
#pragma unroll
        for (int i = 0; i < 4; ++i) {
            int row = w_m + i * 16 + lr;
            int off = row * 32 + ((quad ^ ((row >> 1) & 3)) * 8);
            afh[i] = *(const bf16x8*)(Ahi_s + off);
            afl[i] = *(const bf16x8*)(Alo_s + off);
        }
#pragma unroll
        for (int j = 0; j < 8; ++j) {
            int row = w_n + j * 16 + lr;
            int off = row * 32 + ((quad ^ ((row >> 1) & 3)) * 8);
            bfh[j] = *(const bf16x8*)(Bhi_s + off);
        }
#pragma unroll
        for (int i = 0; i < 4; ++i)
#pragma unroll
            for (int j = 0; j < 8; ++j)
                acc[i][j] = __builtin_amdgcn_mfma_f32_16x16x32_bf16(afh[i], bfh[j], acc[i][j], 0, 0, 0);
#pragma unroll
        for (int i = 0; i < 4; ++i)
#pragma unroll
            for (int j = 0; j < 8; ++j)
                acc[i][j] = __builtin_amdgcn_mfma_f32_16x16x32_bf16(afl[i], bfh[j], acc[i][j], 0, 0, 0);
        __syncthreads();
    }

    // epilogue: relu(C + b1)*w2, reduce over this tile's n, accumulate to logits
    float b1v[8], w2v[8];
#pragma unroll
    for (int j = 0; j < 8; ++j) {
        int n = n0 + w_n + j * 16 + lr;              // C/D col = lane&15
        b1v[j] = b1[n];
        w2v[j] = w2[n];
    }
#pragma unroll
    for (int i = 0; i < 4; ++i) {
#pragma unroll
        for (int r = 0; r < 4; ++r) {
            float s = 0.f;
#pragma unroll
            for (int j = 0; j < 8; ++j) {
                float h = acc[i][j][r] + b1v[j];
                s += fmaxf(h, 0.f) * w2v[j];
            }
            s += __shfl_xor(s, 1, 64);
            s += __shfl_xor(s, 2, 64);
            s += __shfl_xor(s, 4, 64);
            s += __shfl_xor(s, 8, 64);
            if (lr == 0) {
                int m = m0 + w_m + i * 16 + quad * 4 + r;   // C/D row = quad*4 + reg
                atomicAdd(&out[(m & (BATCH - 1)) * T_STEPS + (m >> 2)], s);  // -> [b][t]
            }
        }
    }
}

// ------------- finish: soft output (blocks 0..63) + serial LIF scan (block 64) -------------
// Scan is a 4096-step serial chain; loads are L2-latency-bound if issued in-chain.
// Fix: 16-step register prefetch ring (load chunk c+1 before processing chunk c;
// ~250 cyc of chain work hides the ~200 cyc L2 latency). x+bb2 / rl>0 computed off-chain.
__global__ void __launch_bounds__(256)
finish(const float* __restrict__ logits,
       const float* __restrict__ bb2p, const float* __restrict__ br2p,
       float* __restrict__ out)
{
    if (blockIdx.x < 64) {
        int i = blockIdx.x * 256 + threadIdx.x;
        out[i] = logits[i] + bb2p[0];                // soft = boundary logits [b][t] + bb2
        return;
    }
    int b = threadIdx.x;
    if (b >= BATCH) return;
    const float bb2 = bb2p[0];
    const float br2 = br2p[0];
    const float* xb = logits + b * T_STEPS;          // boundary logits, [b][t]
    const float* xr = logits + M_ROWS + b * T_STEPS; // reset logits
    float* hb = out + M_ROWS + b * T_STEPS;

    float4 cx[4], cr[4], nx[4] = {}, nr[4] = {};
#pragma unroll
    for (int q = 0; q < 4; ++q) {
        cx[q] = *(const float4*)(xb + q * 4);
        cr[q] = *(const float4*)(xr + q * 4);
    }

    float v = 0.f;
    for (int t0 = 0; t0 < T_STEPS; t0 += 16) {
        if (t0 + 16 < T_STEPS) {
#pragma unroll
            for (int q = 0; q < 4; ++q) {
                nx[q] = *(const float4*)(xb + t0 + 16 + q * 4);
                nr[q] = *(const float4*)(xr + t0 + 16 + q * 4);
            }
        }
#pragma unroll
        for (int q = 0; q < 4; ++q) {
            // off-chain precompute (same ops as before, just hoisted)
            float xs[4] = { cx[q].x + bb2, cx[q].y + bb2, cx[q].z + bb2, cx[q].w + bb2 };
            bool  rm[4] = { cr[q].x + br2 > 0.f, cr[q].y + br2 > 0.f,
                            cr[q].z + br2 > 0.f, cr[q].w + br2 > 0.f };
            float4 sv;
#pragma unroll
            for (int u = 0; u < 4; ++u) {
                v = v + (xs[u] - v) * 0.5f;          // bit-identical to reference step
                bool spike = (v >= 1.0f);
                ((float*)&sv)[u] = spike ? 1.0f : 0.0f;
                v = (spike || rm[u]) ? 0.f : v;
            }
            *(float4*)(hb + t0 + q * 4) = sv;
        }
#pragma unroll
        for (int q = 0; q < 4; ++q) { cx[q] = nx[q]; cr[q] = nr[q]; }
    }
}

extern "C" void kernel_launch(void* const* d_in, const int* in_sizes, int n_in,
                              void* d_out, int out_size, void* d_ws, size_t ws_size,
                              hipStream_t stream) {
    // dict order (confirmed): hidden, Wb1, bb1, Wb2, bb2, Wr1, br1, Wr2, br2
    const float* hidden = (const float*)d_in[0];   // [T,B,D] f32
    const float* Wb1    = (const float*)d_in[1];   // [D,H]
    const float* bb1    = (const float*)d_in[2];   // [H]
    const float* Wb2    = (const float*)d_in[3];   // [H,1]
    const float* bb2    = (const float*)d_in[4];   // [1]
    const float* Wr1    = (const float*)d_in[5];
    const float* br1    = (const float*)d_in[6];
    const float* Wr2    = (const float*)d_in[7];
    const float* br2    = (const float*)d_in[8];
    float* out = (float*)d_out;                    // f32: [soft B*T][hard B*T]

    // ws layout (unchanged, 96.13 MB): Xhi 32MB | Xlo 32MB | WThi 16MB | (WTlo unused) | logits
    unsigned short* Xhi  = (unsigned short*)d_ws;
    unsigned short* Xlo  = Xhi  + (size_t)M_ROWS * D_IN;
    unsigned short* WThi = Xlo  + (size_t)M_ROWS * D_IN;
    unsigned short* WTlo = WThi + (size_t)2 * H_DIM * D_IN;   // region kept for layout stability
    float* logits = (float*)(WTlo + (size_t)2 * H_DIM * D_IN);

    prep<<<dim3(6176), 256, 0, stream>>>(hidden, Wb1, Wr1, Xhi, Xlo, WThi, logits);
    gemm_fused2<<<dim3(H_DIM / 256, M_ROWS / 128, 2), 256, 0, stream>>>(
        Xhi, Xlo, WThi, bb1, br1, Wb2, Wr2, logits);
    finish<<<dim3(65), 256, 0, stream>>>(logits, bb2, br2, out);
}